// Round 1
// baseline (156.341 us; speedup 1.0000x reference)
//
#include <hip/hip_runtime.h>
#include <cstdint>

typedef __attribute__((ext_vector_type(8))) __bf16 bf16x8;
typedef __attribute__((ext_vector_type(4))) float f32x4;

// ---- problem constants ----
#define NB   16
#define CIN  256
#define COUT 256
#define HIN  64
#define WIN  64
#define HP   66          // padded H
#define WP   66          // padded W
#define KTOT 2304        // 9*256
#define XPAD_ELEMS (NB*HP*WP*CIN)   // 17,842,176 bf16 elems

__device__ __forceinline__ uint16_t f2bf(float f) {
  uint32_t u = __builtin_bit_cast(uint32_t, f);
  u = (u + 0x7FFFu + ((u >> 16) & 1u)) >> 16;   // round-to-nearest-even
  return (uint16_t)u;
}

// ---------------- transpose + cast: x NCHW fp32 -> xpad[b][h+1][w+1][c] bf16 --------
__global__ void xpose_kernel(const float* __restrict__ x, uint16_t* __restrict__ xpad) {
  __shared__ uint16_t t[64 * 68];   // [w][c], pitch 68 to dodge bank conflicts
  const int tid = threadIdx.x;
  const int cb = blockIdx.x & 3;          // 4 channel blocks of 64
  const int h  = (blockIdx.x >> 2) & 63;
  const int b  = blockIdx.x >> 8;
  const int c0 = cb * 64;
  const float* src = x + (((size_t)(b * 256 + c0) * 64 + h) * 64);
  const int w4 = (tid & 15) * 4;
  #pragma unroll
  for (int it = 0; it < 4; ++it) {
    const int cc = it * 16 + (tid >> 4);
    f32x4 v = *(const f32x4*)(src + cc * 4096 + w4);
    t[(w4 + 0) * 68 + cc] = f2bf(v.x);
    t[(w4 + 1) * 68 + cc] = f2bf(v.y);
    t[(w4 + 2) * 68 + cc] = f2bf(v.z);
    t[(w4 + 3) * 68 + cc] = f2bf(v.w);
  }
  __syncthreads();
  uint16_t* dstbase = xpad + ((size_t)(b * HP + h + 1) * WP + 1) * 256 + c0;
  #pragma unroll
  for (int it = 0; it < 4; ++it) {
    const int slot = it * 256 + tid;
    const int w = slot >> 4, c4 = slot & 15;
    const uint32_t* s2 = (const uint32_t*)&t[w * 68 + c4 * 4];
    uint32_t* d2 = (uint32_t*)(dstbase + w * 256 + c4 * 4);
    d2[0] = s2[0];
    d2[1] = s2[1];
  }
}

// ---------------- weight reorder: w[co][ci][kh][kw] fp32 -> Bw[co][tap][ci] bf16 ----
__global__ void wprep_kernel(const float* __restrict__ w, uint16_t* __restrict__ bw) {
  const int o = blockIdx.x * 256 + threadIdx.x;   // 0 .. 589823
  const int co = o / KTOT;
  const int r  = o - co * KTOT;
  const int tap = r >> 8;
  const int ci  = r & 255;
  bw[o] = f2bf(w[(co * 256 + ci) * 9 + tap]);
}

// ---------------- async 16B global -> LDS --------------------------------------------
__device__ __forceinline__ void gl_lds16(const void* g, void* l) {
  __builtin_amdgcn_global_load_lds(
      (__attribute__((address_space(1))) void*)(uintptr_t)g,
      (__attribute__((address_space(3))) void*)(uint32_t)(uintptr_t)l,
      16, 0, 0);
}

// ---------------- implicit GEMM: C[m][n], m=(b,perm-q), n=co, K=tap*256+ci -----------
// BM=128, BN=64, BK=64; 256 threads (4 waves), wave tile 32x64 (2x4 MFMA 16x16x32)
__global__ __launch_bounds__(256, 2) void gemm_kernel(
    const uint16_t* __restrict__ xpad, const uint16_t* __restrict__ bw,
    const float* __restrict__ bias, float* __restrict__ out) {
  __shared__ uint16_t lA[128 * 64];
  __shared__ uint16_t lB[64 * 64];
  const int tid = threadIdx.x;
  const int wv = tid >> 6, lane = tid & 63;
  const int quad = lane >> 4, l15 = lane & 15, l7 = lane & 7;
  const int ntile = blockIdx.x & 3;
  const int mtile = blockIdx.x >> 2;
  const int n0 = ntile * 64;
  const int m0 = mtile * 128;
  const int bidx = m0 >> 10;       // batch index (128 rows stay within one b)
  const int q0 = m0 & 1023;        // permuted pixel offset within the batch image

  // A staging: 4 slots/thread; decode permuted row -> input coords; XOR chunk swizzle
  int a_goff[4];
  #pragma unroll
  for (int t = 0; t < 4; ++t) {
    const int slot = t * 256 + tid;
    const int row = slot >> 3;
    const int ch = (slot & 7) ^ (row & 7);
    const int p = q0 + row;
    const int oh = 2 * ((p >> 4) & 15) + ((p >> 9) & 1);
    const int ow = 2 * (p & 15) + ((p >> 8) & 1);
    // padded coords: h_pad = 2*oh + kh, w_pad = 2*ow + kw (tap offset added later)
    a_goff[t] = ((bidx * HP + 2 * oh) * WP + 2 * ow) * 256 + ch * 8;
  }
  // B staging: 2 slots/thread
  int b_goff[2];
  #pragma unroll
  for (int t = 0; t < 2; ++t) {
    const int slot = t * 256 + tid;
    const int n = slot >> 3;
    const int kc = (slot & 7) ^ (n & 7);
    b_goff[t] = (n0 + n) * KTOT + kc * 8;
  }

  // LDS frag read byte-offsets (swizzle-matched)
  int aoff[2][2], boff[4][2];
  #pragma unroll
  for (int r = 0; r < 2; ++r)
    #pragma unroll
    for (int s = 0; s < 2; ++s)
      aoff[r][s] = (wv * 32 + r * 16 + l15) * 128 + (((s * 4 + quad) ^ l7) * 16);
  #pragma unroll
  for (int c = 0; c < 4; ++c)
    #pragma unroll
    for (int s = 0; s < 2; ++s)
      boff[c][s] = (c * 16 + l15) * 128 + (((s * 4 + quad) ^ l7) * 16);

  f32x4 acc[2][4];
  #pragma unroll
  for (int r = 0; r < 2; ++r)
    #pragma unroll
    for (int c = 0; c < 4; ++c)
      acc[r][c] = (f32x4){0.f, 0.f, 0.f, 0.f};

  char* lAc = (char*)lA;
  char* lBc = (char*)lB;

  for (int tap = 0; tap < 9; ++tap) {
    const int kh = tap / 3, kw = tap - kh * 3;
    const uint16_t* aptr = xpad + (kh * WP + kw) * 256;
    const uint16_t* bptr = bw + tap * 256;
    for (int ci0 = 0; ci0 < 256; ci0 += 64) {
      __syncthreads();   // previous iteration done reading LDS
      #pragma unroll
      for (int t = 0; t < 4; ++t)
        gl_lds16(aptr + a_goff[t] + ci0, lAc + (t * 256 + wv * 64) * 16);
      #pragma unroll
      for (int t = 0; t < 2; ++t)
        gl_lds16(bptr + b_goff[t] + ci0, lBc + (t * 256 + wv * 64) * 16);
      __syncthreads();   // drains vmcnt(0) -> LDS tiles ready
      #pragma unroll
      for (int s = 0; s < 2; ++s) {
        bf16x8 af[2], bfr[4];
        #pragma unroll
        for (int r = 0; r < 2; ++r) af[r] = *(const bf16x8*)(lAc + aoff[r][s]);
        #pragma unroll
        for (int c = 0; c < 4; ++c) bfr[c] = *(const bf16x8*)(lBc + boff[c][s]);
        #pragma unroll
        for (int r = 0; r < 2; ++r)
          #pragma unroll
          for (int c = 0; c < 4; ++c)
            acc[r][c] = __builtin_amdgcn_mfma_f32_16x16x32_bf16(af[r], bfr[c], acc[r][c], 0, 0, 0);
      }
    }
  }

  // epilogue: D row = m (quad*4+reg -> 4 consecutive permuted pixels), col = co
  float* obase = out + (size_t)bidx * (COUT * 1024);
  #pragma unroll
  for (int c = 0; c < 4; ++c) {
    const int co = n0 + c * 16 + l15;
    const float bv = bias[co];
    #pragma unroll
    for (int r = 0; r < 2; ++r) {
      const int q = q0 + wv * 32 + r * 16 + quad * 4;
      f32x4 v = acc[r][c];
      v += bv;
      *(f32x4*)(obase + co * 1024 + q) = v;
    }
  }
}

extern "C" void kernel_launch(void* const* d_in, const int* in_sizes, int n_in,
                              void* d_out, int out_size, void* d_ws, size_t ws_size,
                              hipStream_t stream) {
  const float* x    = (const float*)d_in[0];
  const float* w    = (const float*)d_in[1];
  const float* bias = (const float*)d_in[2];
  float* out = (float*)d_out;
  uint16_t* xpad = (uint16_t*)d_ws;
  uint16_t* bwq  = xpad + XPAD_ELEMS;          // 256*2304 bf16

  hipMemsetAsync(xpad, 0, (size_t)XPAD_ELEMS * sizeof(uint16_t), stream);
  xpose_kernel<<<dim3(16 * 64 * 4), dim3(256), 0, stream>>>(x, xpad);
  wprep_kernel<<<dim3(KTOT), dim3(256), 0, stream>>>(w, bwq);
  gemm_kernel<<<dim3(512), dim3(256), 0, stream>>>(xpad, bwq, bias, out);
}

// Round 2
// 150.710 us; speedup vs baseline: 1.0374x; 1.0374x over previous
//
#include <hip/hip_runtime.h>
#include <cstdint>

typedef __attribute__((ext_vector_type(8))) __bf16 bf16x8;
typedef __attribute__((ext_vector_type(4))) float f32x4;
typedef __attribute__((ext_vector_type(4))) uint32_t u32x4;

// ---- problem constants ----
#define NB   16
#define CIN  256
#define COUT 256
#define HP   66          // padded H
#define WP   66          // padded W
#define KTOT 2304        // 9*256
#define XPB  (HP*WP*256)            // elems per batch image = 1,115,136
#define XPAD_ELEMS (NB*XPB)

__device__ __forceinline__ uint16_t f2bf(float f) {
  uint32_t u = __builtin_bit_cast(uint32_t, f);
  u = (u + 0x7FFFu + ((u >> 16) & 1u)) >> 16;   // round-to-nearest-even
  return (uint16_t)u;
}

// ---------------- zero the pad border of xpad (2.1 MB instead of 36 MB memset) ------
__global__ void border_kernel(uint16_t* __restrict__ xpad) {
  const int idx = blockIdx.x * 256 + threadIdx.x;   // 0 .. 266239 (exact)
  const int b = idx / 16640;
  const int r = idx - b * 16640;
  uint64_t* base = (uint64_t*)(xpad + (size_t)b * XPB);
  int off;
  if (r < 4224) {                    // h=0 full row (66*256 elems = 4224 u64)
    off = r;
  } else if (r < 8448) {             // h=65 full row
    off = 274560 + (r - 4224);       // 65*4224
  } else if (r < 12544) {            // w=0 column, h=1..64
    const int i = r - 8448;
    off = (1 + (i >> 6)) * 4224 + (i & 63);
  } else {                           // w=65 column, h=1..64
    const int i = r - 12544;
    off = (1 + (i >> 6)) * 4224 + 4160 + (i & 63);   // 65*256/4 = 4160
  }
  base[off] = 0;
}

// ---------------- transpose+cast, no LDS: x NCHW fp32 -> xpad[b][h+1][w+1][c] bf16 --
// lanes = w (coalesced dword reads); each lane packs 32 ch -> 64 B contiguous store
__global__ void xpose_kernel(const float* __restrict__ x, uint16_t* __restrict__ xpad) {
  const int lane = threadIdx.x & 63;
  const int wv = threadIdx.x >> 6;            // 0..3
  const int chalf = blockIdx.x & 1;
  const int h = (blockIdx.x >> 1) & 63;
  const int b = blockIdx.x >> 7;
  const int c0 = chalf * 128 + wv * 32;
  const float* src = x + ((size_t)(b * 256 + c0) * 64 + h) * 64 + lane;
  uint16_t* dst = xpad + ((size_t)(b * HP + h + 1) * WP + lane + 1) * 256 + c0;
  #pragma unroll
  for (int g = 0; g < 4; ++g) {               // 8 channels per 16B store
    u32x4 d;
    #pragma unroll
    for (int k = 0; k < 4; ++k) {
      const float v0 = src[(size_t)(g * 8 + 2 * k + 0) * 4096];
      const float v1 = src[(size_t)(g * 8 + 2 * k + 1) * 4096];
      d[k] = (uint32_t)f2bf(v0) | ((uint32_t)f2bf(v1) << 16);
    }
    *(u32x4*)(dst + g * 8) = d;
  }
}

// ---------------- weight reorder: w[co][ci][kh][kw] fp32 -> Bw[co][tap][ci] bf16 ----
__global__ void wprep_kernel(const float* __restrict__ w, uint16_t* __restrict__ bw) {
  const int gid = blockIdx.x * 256 + threadIdx.x;   // 0 .. 73727
  const int co = gid / 288;                         // 288 = 9 taps * 32 ci-groups
  const int r = gid - co * 288;
  const int tap = r >> 5;
  const int ci0 = (r & 31) * 8;
  u32x4 d;
  #pragma unroll
  for (int k = 0; k < 4; ++k) {
    const float v0 = w[((co * 256 + ci0 + 2 * k + 0) * 9) + tap];
    const float v1 = w[((co * 256 + ci0 + 2 * k + 1) * 9) + tap];
    d[k] = (uint32_t)f2bf(v0) | ((uint32_t)f2bf(v1) << 16);
  }
  *(u32x4*)(bw + co * KTOT + tap * 256 + ci0) = d;
}

// ---------------- async 16B global -> LDS --------------------------------------------
__device__ __forceinline__ void gl_lds16(const void* g, void* l) {
  __builtin_amdgcn_global_load_lds(
      (__attribute__((address_space(1))) void*)(uintptr_t)g,
      (__attribute__((address_space(3))) void*)(uint32_t)(uintptr_t)l,
      16, 0, 0);
}

// ---------------- implicit GEMM: BM=128, BN=64, BK=64; 128 threads (2 waves) --------
// wave tile 64x64 (4x4 MFMA 16x16x32), double-buffered LDS, XCD-swizzled blocks
__global__ __launch_bounds__(128, 2) void gemm_kernel(
    const uint16_t* __restrict__ xpad, const uint16_t* __restrict__ bw,
    const float* __restrict__ bias, float* __restrict__ out) {
  __shared__ uint16_t lA[2][128 * 64];   // 16 KB per buffer
  __shared__ uint16_t lB[2][64 * 64];    //  8 KB per buffer
  const int tid = threadIdx.x;
  const int wv = tid >> 6, lane = tid & 63;
  const int quad = lane >> 4, l15 = lane & 15, l7 = lane & 7;

  // XCD swizzle: the 4 n-tiles of one m-tile land on the same XCD, adjacent in time
  const int xcd = blockIdx.x & 7;
  const int grp = blockIdx.x >> 3;        // 0..63 per XCD
  const int mtile = (xcd << 4) + (grp >> 2);
  const int ntile = grp & 3;
  const int n0 = ntile * 64;
  const int m0 = mtile * 128;
  const int bidx = m0 >> 10;              // batch image
  const int q0 = m0 & 1023;               // permuted pixel offset (multiple of 128)

  // A staging: 8 chunk-slots/thread (1024 chunks of 16B)
  int a_goff[8];
  #pragma unroll
  for (int t = 0; t < 8; ++t) {
    const int c = t * 128 + tid;
    const int row = c >> 3;
    const int kc = (c & 7) ^ (row & 7);          // XOR chunk swizzle
    const int p = q0 + row;
    const int oh = 2 * ((p >> 4) & 15) + ((p >> 9) & 1);
    const int ow = 2 * (p & 15) + ((p >> 8) & 1);
    a_goff[t] = ((bidx * HP + 2 * oh) * WP + 2 * ow) * 256 + kc * 8;
  }
  // B staging: 4 chunk-slots/thread (512 chunks)
  int b_goff[4];
  #pragma unroll
  for (int t = 0; t < 4; ++t) {
    const int c = t * 128 + tid;
    const int n = c >> 3;
    const int kc = (c & 7) ^ (n & 7);
    b_goff[t] = (n0 + n) * KTOT + kc * 8;
  }

  // LDS frag byte-offsets (swizzle-matched)
  int aoff[4][2], boff[4][2];
  #pragma unroll
  for (int r = 0; r < 4; ++r)
    #pragma unroll
    for (int s = 0; s < 2; ++s)
      aoff[r][s] = (wv * 64 + r * 16 + l15) * 128 + (((s * 4 + quad) ^ l7) * 16);
  #pragma unroll
  for (int c = 0; c < 4; ++c)
    #pragma unroll
    for (int s = 0; s < 2; ++s)
      boff[c][s] = (c * 16 + l15) * 128 + (((s * 4 + quad) ^ l7) * 16);

  f32x4 acc[4][4];
  #pragma unroll
  for (int r = 0; r < 4; ++r)
    #pragma unroll
    for (int c = 0; c < 4; ++c)
      acc[r][c] = (f32x4){0.f, 0.f, 0.f, 0.f};

  auto stage = [&](int it, int buf) {
    const int tap = it >> 2;
    const int kh = tap / 3, kw = tap - kh * 3;
    const int ci0 = (it & 3) << 6;
    const uint16_t* aptr = xpad + (kh * WP + kw) * 256 + ci0;
    const uint16_t* bptr = bw + tap * 256 + ci0;
    char* la = (char*)&lA[buf][0];
    char* lb = (char*)&lB[buf][0];
    #pragma unroll
    for (int t = 0; t < 8; ++t)
      gl_lds16(aptr + a_goff[t], la + (t * 128 + wv * 64) * 16);
    #pragma unroll
    for (int t = 0; t < 4; ++t)
      gl_lds16(bptr + b_goff[t], lb + (t * 128 + wv * 64) * 16);
  };

  stage(0, 0);
  int buf = 0;
  for (int it = 0; it < 36; ++it) {
    __syncthreads();               // drains vmcnt -> lA/lB[buf] ready; buf^1 free
    if (it < 35) stage(it + 1, buf ^ 1);
    const char* la = (const char*)&lA[buf][0];
    const char* lb = (const char*)&lB[buf][0];
    #pragma unroll
    for (int s = 0; s < 2; ++s) {
      bf16x8 af[4], bfr[4];
      #pragma unroll
      for (int r = 0; r < 4; ++r) af[r] = *(const bf16x8*)(la + aoff[r][s]);
      #pragma unroll
      for (int c = 0; c < 4; ++c) bfr[c] = *(const bf16x8*)(lb + boff[c][s]);
      #pragma unroll
      for (int r = 0; r < 4; ++r)
        #pragma unroll
        for (int c = 0; c < 4; ++c)
          acc[r][c] = __builtin_amdgcn_mfma_f32_16x16x32_bf16(af[r], bfr[c], acc[r][c], 0, 0, 0);
    }
    buf ^= 1;
  }

  // epilogue: row(M) = wv*64 + r*16 + quad*4 + reg, col(N) = c*16 + l15
  float* obase = out + (size_t)bidx * (COUT * 1024);
  #pragma unroll
  for (int c = 0; c < 4; ++c) {
    const int co = n0 + c * 16 + l15;
    const float bv = bias[co];
    #pragma unroll
    for (int r = 0; r < 4; ++r) {
      const int q = q0 + wv * 64 + r * 16 + quad * 4;
      f32x4 v = acc[r][c];
      v += bv;
      *(f32x4*)(obase + (size_t)co * 1024 + q) = v;
    }
  }
}

extern "C" void kernel_launch(void* const* d_in, const int* in_sizes, int n_in,
                              void* d_out, int out_size, void* d_ws, size_t ws_size,
                              hipStream_t stream) {
  const float* x    = (const float*)d_in[0];
  const float* w    = (const float*)d_in[1];
  const float* bias = (const float*)d_in[2];
  float* out = (float*)d_out;
  uint16_t* xpad = (uint16_t*)d_ws;
  uint16_t* bwq  = xpad + XPAD_ELEMS;          // 256*2304 bf16

  border_kernel<<<dim3(1040), dim3(256), 0, stream>>>(xpad);
  xpose_kernel<<<dim3(2048), dim3(256), 0, stream>>>(x, xpad);
  wprep_kernel<<<dim3(288), dim3(256), 0, stream>>>(w, bwq);
  gemm_kernel<<<dim3(512), dim3(128), 0, stream>>>(xpad, bwq, bias, out);
}

// Round 3
// 138.534 us; speedup vs baseline: 1.1285x; 1.0879x over previous
//
#include <hip/hip_runtime.h>
#include <cstdint>

typedef __attribute__((ext_vector_type(8))) __bf16 bf16x8;
typedef __attribute__((ext_vector_type(4))) float f32x4;
typedef __attribute__((ext_vector_type(4))) uint32_t u32x4;

// ---- problem constants ----
#define NB   16
#define CIN  256
#define COUT 256
#define HP   66          // padded H
#define WP   66          // padded W
#define KTOT 2304        // 9*256
#define XPB  (HP*WP*256)            // elems per batch image = 1,115,136
#define XPAD_ELEMS (NB*XPB)

__device__ __forceinline__ uint16_t f2bf(float f) {
  uint32_t u = __builtin_bit_cast(uint32_t, f);
  u = (u + 0x7FFFu + ((u >> 16) & 1u)) >> 16;   // round-to-nearest-even
  return (uint16_t)u;
}

// ---------------- fused prep: xpose (2048 blk) | border (1040 blk) | wprep (288 blk)
__global__ void prep_kernel(const float* __restrict__ x, const float* __restrict__ w,
                            uint16_t* __restrict__ xpad, uint16_t* __restrict__ bw) {
  const int bid = blockIdx.x;
  const int tid = threadIdx.x;
  if (bid < 2048) {
    // transpose+cast: x NCHW fp32 -> xpad[b][h+1][w+1][c] bf16 (interior only)
    const int lane = tid & 63;
    const int wvi = tid >> 6;                 // 0..3
    const int chalf = bid & 1;
    const int h = (bid >> 1) & 63;
    const int b = bid >> 7;
    const int c0 = chalf * 128 + wvi * 32;
    const float* src = x + ((size_t)(b * 256 + c0) * 64 + h) * 64 + lane;
    uint16_t* dst = xpad + ((size_t)(b * HP + h + 1) * WP + lane + 1) * 256 + c0;
    #pragma unroll
    for (int g = 0; g < 4; ++g) {             // 8 channels per 16B store
      u32x4 d;
      #pragma unroll
      for (int k = 0; k < 4; ++k) {
        const float v0 = src[(size_t)(g * 8 + 2 * k + 0) * 4096];
        const float v1 = src[(size_t)(g * 8 + 2 * k + 1) * 4096];
        d[k] = (uint32_t)f2bf(v0) | ((uint32_t)f2bf(v1) << 16);
      }
      *(u32x4*)(dst + g * 8) = d;
    }
  } else if (bid < 3088) {
    // zero the pad border (u64 stores)
    const int idx = (bid - 2048) * 256 + tid;   // 0 .. 266239 exact
    const int b = idx / 16640;
    const int r = idx - b * 16640;
    uint64_t* base = (uint64_t*)(xpad + (size_t)b * XPB);
    int off;
    if (r < 4224) {                    // h=0 full row
      off = r;
    } else if (r < 8448) {             // h=65 full row
      off = 274560 + (r - 4224);
    } else if (r < 12544) {            // w=0 column, h=1..64
      const int i = r - 8448;
      off = (1 + (i >> 6)) * 4224 + (i & 63);
    } else {                           // w=65 column, h=1..64
      const int i = r - 12544;
      off = (1 + (i >> 6)) * 4224 + 4160 + (i & 63);
    }
    base[off] = 0;
  } else {
    // weight reorder: w[co][ci][3][3] fp32 -> bw[co][tap][ci] bf16
    const int gid = (bid - 3088) * 256 + tid;   // 0 .. 73727
    const int co = gid / 288;                   // 288 = 9 taps * 32 ci-groups
    const int r = gid - co * 288;
    const int tap = r >> 5;
    const int ci0 = (r & 31) * 8;
    u32x4 d;
    #pragma unroll
    for (int k = 0; k < 4; ++k) {
      const float v0 = w[((co * 256 + ci0 + 2 * k + 0) * 9) + tap];
      const float v1 = w[((co * 256 + ci0 + 2 * k + 1) * 9) + tap];
      d[k] = (uint32_t)f2bf(v0) | ((uint32_t)f2bf(v1) << 16);
    }
    *(u32x4*)(bw + co * KTOT + tap * 256 + ci0) = d;
  }
}

// ---------------- async 16B global -> LDS --------------------------------------------
__device__ __forceinline__ void gl_lds16(const void* g, void* l) {
  __builtin_amdgcn_global_load_lds(
      (__attribute__((address_space(1))) void*)(uintptr_t)g,
      (__attribute__((address_space(3))) void*)(uint32_t)(uintptr_t)l,
      16, 0, 0);
}

// ---------------- implicit GEMM: BM=128, BN=64, BK=64; 256 threads (4 waves) --------
// wave tile 32x64 (2x4 MFMA 16x16x32), double-buffered LDS, XCD-swizzled blocks
// 512 blocks -> 2 blocks/CU -> 8 waves/CU (2/SIMD) for latency hiding
__global__ __launch_bounds__(256, 2) void gemm_kernel(
    const uint16_t* __restrict__ xpad, const uint16_t* __restrict__ bw,
    const float* __restrict__ bias, float* __restrict__ out) {
  __shared__ uint16_t lA[2][128 * 64];   // 16 KB per buffer
  __shared__ uint16_t lB[2][64 * 64];    //  8 KB per buffer
  const int tid = threadIdx.x;
  const int wv = tid >> 6, lane = tid & 63;
  const int quad = lane >> 4, l15 = lane & 15, l7 = lane & 7;

  // XCD swizzle: 4 n-tiles of one m-tile co-resident on one XCD -> A fetched ~once
  const int xcd = blockIdx.x & 7;
  const int grp = blockIdx.x >> 3;        // 0..63 per XCD
  const int mtile = (xcd << 4) + (grp >> 2);
  const int ntile = grp & 3;
  const int n0 = ntile * 64;
  const int m0 = mtile * 128;
  const int bidx = m0 >> 10;              // batch image
  const int q0 = m0 & 1023;               // permuted pixel offset (multiple of 128)

  // A staging: 4 chunk-slots/thread (1024 chunks of 16B); XOR chunk swizzle
  int a_goff[4];
  #pragma unroll
  for (int t = 0; t < 4; ++t) {
    const int slot = t * 256 + tid;
    const int row = slot >> 3;
    const int kc = (slot & 7) ^ (row & 7);
    const int p = q0 + row;
    const int oh = 2 * ((p >> 4) & 15) + ((p >> 9) & 1);
    const int ow = 2 * (p & 15) + ((p >> 8) & 1);
    a_goff[t] = ((bidx * HP + 2 * oh) * WP + 2 * ow) * 256 + kc * 8;
  }
  // B staging: 2 chunk-slots/thread (512 chunks)
  int b_goff[2];
  #pragma unroll
  for (int t = 0; t < 2; ++t) {
    const int slot = t * 256 + tid;
    const int n = slot >> 3;
    const int kc = (slot & 7) ^ (n & 7);
    b_goff[t] = (n0 + n) * KTOT + kc * 8;
  }

  // LDS frag byte-offsets (swizzle-matched)
  int aoff[2][2], boff[4][2];
  #pragma unroll
  for (int r = 0; r < 2; ++r)
    #pragma unroll
    for (int s = 0; s < 2; ++s)
      aoff[r][s] = (wv * 32 + r * 16 + l15) * 128 + (((s * 4 + quad) ^ l7) * 16);
  #pragma unroll
  for (int c = 0; c < 4; ++c)
    #pragma unroll
    for (int s = 0; s < 2; ++s)
      boff[c][s] = (c * 16 + l15) * 128 + (((s * 4 + quad) ^ l7) * 16);

  f32x4 acc[2][4];
  #pragma unroll
  for (int r = 0; r < 2; ++r)
    #pragma unroll
    for (int c = 0; c < 4; ++c)
      acc[r][c] = (f32x4){0.f, 0.f, 0.f, 0.f};

  auto stage = [&](int it, int buf) {
    const int tap = it >> 2;
    const int kh = tap / 3, kw = tap - kh * 3;
    const int ci0 = (it & 3) << 6;
    const uint16_t* aptr = xpad + (kh * WP + kw) * 256 + ci0;
    const uint16_t* bptr = bw + tap * 256 + ci0;
    char* la = (char*)&lA[buf][0];
    char* lb = (char*)&lB[buf][0];
    #pragma unroll
    for (int t = 0; t < 4; ++t)
      gl_lds16(aptr + a_goff[t], la + (t * 256 + wv * 64) * 16);
    #pragma unroll
    for (int t = 0; t < 2; ++t)
      gl_lds16(bptr + b_goff[t], lb + (t * 256 + wv * 64) * 16);
  };

  stage(0, 0);
  int buf = 0;
  for (int it = 0; it < 36; ++it) {
    __syncthreads();               // lA/lB[buf] ready (stage issued one phase ago)
    if (it < 35) stage(it + 1, buf ^ 1);
    const char* la = (const char*)&lA[buf][0];
    const char* lb = (const char*)&lB[buf][0];
    #pragma unroll
    for (int s = 0; s < 2; ++s) {
      bf16x8 af[2], bfr[4];
      #pragma unroll
      for (int r = 0; r < 2; ++r) af[r] = *(const bf16x8*)(la + aoff[r][s]);
      #pragma unroll
      for (int c = 0; c < 4; ++c) bfr[c] = *(const bf16x8*)(lb + boff[c][s]);
      #pragma unroll
      for (int r = 0; r < 2; ++r)
        #pragma unroll
        for (int c = 0; c < 4; ++c)
          acc[r][c] = __builtin_amdgcn_mfma_f32_16x16x32_bf16(af[r], bfr[c], acc[r][c], 0, 0, 0);
    }
    buf ^= 1;
  }

  // epilogue: row(M) = wv*32 + r*16 + quad*4 + reg, col(N) = c*16 + l15
  float* obase = out + (size_t)bidx * (COUT * 1024);
  #pragma unroll
  for (int c = 0; c < 4; ++c) {
    const int co = n0 + c * 16 + l15;
    const float bv = bias[co];
    #pragma unroll
    for (int r = 0; r < 2; ++r) {
      const int q = q0 + wv * 32 + r * 16 + quad * 4;
      f32x4 v = acc[r][c];
      v += bv;
      *(f32x4*)(obase + (size_t)co * 1024 + q) = v;
    }
  }
}

extern "C" void kernel_launch(void* const* d_in, const int* in_sizes, int n_in,
                              void* d_out, int out_size, void* d_ws, size_t ws_size,
                              hipStream_t stream) {
  const float* x    = (const float*)d_in[0];
  const float* w    = (const float*)d_in[1];
  const float* bias = (const float*)d_in[2];
  float* out = (float*)d_out;
  uint16_t* xpad = (uint16_t*)d_ws;
  uint16_t* bwq  = xpad + XPAD_ELEMS;          // 256*2304 bf16

  prep_kernel<<<dim3(3376), dim3(256), 0, stream>>>(x, w, xpad, bwq);
  gemm_kernel<<<dim3(512), dim3(256), 0, stream>>>(xpad, bwq, bias, out);
}